// Round 12
// baseline (130.039 us; speedup 1.0000x reference)
//
#include <hip/hip_runtime.h>

// UltralyticsDetect head, fused: per-level 1x1-conv GEMM (M=144, K=C, N=B*HW)
// in bf16 MFMA + in-register DFL softmax decode + output assembly.
// Output: (16, 8400, 84) f32.
//
// R12: ZERO-LDS, ZERO-BARRIER, ZERO-INLINE-ASM register-resident pipeline.
// Every prior round (R6-R11, all ~48-60us) had LDS staging + explicit waits
// pinning the per-iter critical path (global_load_lds forces a hard drain
// before first use; hand vmcnt/barriers defeat the compiler scheduler).
// Here: X -> named P/Q reg double-buffer (issued one chunk ahead), W frags
// (frag-major, L2-hot) -> regs per iter, compiler emits counted vmcnt and
// hoists freely across iterations. Waves fully independent; occupancy
// VGPR-capped only: __launch_bounds__(256,3) = 12 waves/CU.

typedef __bf16 bf16x8 __attribute__((ext_vector_type(8)));
typedef float  f32x4  __attribute__((ext_vector_type(4)));

#define NTHREADS 256

// W image in d_ws: per level, C/32 chunks of 9 KiB (9 m-tiles x 1 KiB frag).
#define WCHUNK 9216
#define WOFF0 0
#define WOFF1 73728              // level0: 8 chunks * 9216
#define WOFF2 221184             // + level1: 16 chunks * 9216

// round-half-up f32 -> bf16, pack two into one u32 (a -> low16, b -> high16)
__device__ __forceinline__ unsigned int pack_bf16(float a, float b) {
    unsigned int ua = __builtin_bit_cast(unsigned int, a);
    unsigned int ub = __builtin_bit_cast(unsigned int, b);
    return ((ua + 0x8000u) >> 16) | ((ub + 0x8000u) & 0xffff0000u);
}

// ---------------- prep kernel: W f32 -> bf16 fragment-major in d_ws --------
// Frag layout: ws[off + kc*9216 + m*1024 + lane*16] = 8 bf16 of
// W[m*16 + (lane&15)][kc*32 + (lane>>4)*8 + j], j=0..7.
__global__ __launch_bounds__(256)
void prep_w_kernel(const float* __restrict__ wb0, const float* __restrict__ wc0,
                   const float* __restrict__ wb1, const float* __restrict__ wc1,
                   const float* __restrict__ wb2, const float* __restrict__ wc2,
                   unsigned char* __restrict__ ws) {
    int uid = blockIdx.x * 256 + threadIdx.x;   // one unit = 8 k-elems
    if (uid >= 23040) return;                   // 4608 + 9216 + 9216
    const float* wb; const float* wc; int C; size_t off; int uu;
    if (uid < 4608)       { wb = wb0; wc = wc0; C = 256; off = WOFF0; uu = uid; }
    else if (uid < 13824) { wb = wb1; wc = wc1; C = 512; off = WOFF1; uu = uid - 4608; }
    else                  { wb = wb2; wc = wc2; C = 512; off = WOFF2; uu = uid - 13824; }
    const int kunits = C / 8;
    const int row = uu / kunits;
    const int k   = (uu % kunits) * 8;
    const float* src = ((row < 64) ? (wb + row * C) : (wc + (row - 64) * C)) + k;
    const float4 f0 = *(const float4*)(src);
    const float4 f1 = *(const float4*)(src + 4);
    uint4 p;
    p.x = pack_bf16(f0.x, f0.y);
    p.y = pack_bf16(f0.z, f0.w);
    p.z = pack_bf16(f1.x, f1.y);
    p.w = pack_bf16(f1.z, f1.w);
    const int kc   = k >> 5;
    const int m    = row >> 4;
    const int lane = (row & 15) | (((k & 31) >> 3) << 4);
    *(uint4*)(ws + off + (size_t)kc * WCHUNK + m * 1024 + lane * 16) = p;
}

// ---------------- main kernel ----------------------------------------------
__global__ __launch_bounds__(NTHREADS, 3)
void UltralyticsDetect_kernel(
        const float* __restrict__ x0, const float* __restrict__ x1, const float* __restrict__ x2,
        const unsigned char* __restrict__ wimg,
        const float* __restrict__ bb0, const float* __restrict__ bc0,
        const float* __restrict__ bb1, const float* __restrict__ bc1,
        const float* __restrict__ bb2, const float* __restrict__ bc2,
        float* __restrict__ out) {

    // ---- runtime level decode (single code path; long levels first) ----
    // level 1: 16 b * 13 tiles = 208 ; level 2: 16*4 = 64 ; level 0: 16*50 = 800
    const int bid = blockIdx.x;
    const float* x; const float* bbox; const float* bcls;
    int C, GW, HW, AOFF, TPB, rb; float STRIDE; size_t WOFF;
    if (bid < 208) {
        x = x1; bbox = bb1; bcls = bc1; rb = bid;
        C = 512; GW = 40; HW = 1600; AOFF = 6400; TPB = 13; STRIDE = 16.0f; WOFF = WOFF1;
    } else if (bid < 272) {
        x = x2; bbox = bb2; bcls = bc2; rb = bid - 208;
        C = 512; GW = 20; HW = 400;  AOFF = 8000; TPB = 4;  STRIDE = 32.0f; WOFF = WOFF2;
    } else {
        x = x0; bbox = bb0; bcls = bc0; rb = bid - 272;
        C = 256; GW = 80; HW = 6400; AOFF = 0;    TPB = 50; STRIDE = 8.0f;  WOFF = WOFF0;
    }
    const int nkc = C / 32;   // 8 or 16, always even

    const int b    = rb / TPB;
    const int tile = rb - b * TPB;
    int hw0 = tile * 128;
    if (hw0 > HW - 128) hw0 = HW - 128;   // tail tiles overlap previous tile

    const int tid  = threadIdx.x;
    const int wv   = tid >> 6;        // wave 0..3
    const int lane = tid & 63;
    const int col  = lane & 15;       // MFMA n/col lane
    const int q4   = lane >> 4;       // MFMA row-quarter

    // X addressing: SGPR-friendly byte base + per-lane voffsets.
    const char* xbyte = (const char*)(x + (size_t)b * C * HW + hw0);
    const int a0 = wv * 32 + col;            // this lane's anchor, frag A
    const int voff0 = (a0 + q4 * 8 * HW) * 4;
    const int voff1 = voff0 + 16 * 4;        // frag B: anchor +16
    const unsigned char* wlev = wimg + WOFF + (size_t)lane * 16;

    f32x4 acc[9][2];
#pragma unroll
    for (int m = 0; m < 9; ++m) {
        acc[m][0] = (f32x4){0.f, 0.f, 0.f, 0.f};
        acc[m][1] = (f32x4){0.f, 0.f, 0.f, 0.f};
    }

    float P0[8], P1[8], Q0[8], Q1[8];   // X double-buffer (static-indexed)
    bf16x8 WE[9], WO[9];                // W frags, even/odd chunk

#define XLOAD(V0, V1, CC)                                                   \
    {                                                                       \
        const char* _xb = xbyte + (size_t)(CC) * 32 * HW * 4;               \
        _Pragma("unroll")                                                   \
        for (int _j = 0; _j < 8; ++_j) {                                    \
            V0[_j] = *(const float*)(_xb + voff0 + _j * HW * 4);            \
            V1[_j] = *(const float*)(_xb + voff1 + _j * HW * 4);            \
        }                                                                   \
    }

#define WLOAD(WF, CC)                                                       \
    {                                                                       \
        const unsigned char* _wk = wlev + (size_t)(CC) * WCHUNK;            \
        _Pragma("unroll")                                                   \
        for (int _m = 0; _m < 9; ++_m)                                      \
            WF[_m] = *(const bf16x8*)(_wk + _m * 1024);                     \
    }

#define CVT(V, DST)                                                         \
    {                                                                       \
        uint4 _q;                                                           \
        _q.x = pack_bf16(V[0], V[1]);                                       \
        _q.y = pack_bf16(V[2], V[3]);                                       \
        _q.z = pack_bf16(V[4], V[5]);                                       \
        _q.w = pack_bf16(V[6], V[7]);                                       \
        DST = __builtin_bit_cast(bf16x8, _q);                               \
    }

#define MFMA18(WF, FA, FB)                                                  \
    {                                                                       \
        _Pragma("unroll")                                                   \
        for (int _m = 0; _m < 9; ++_m) {                                    \
            acc[_m][0] = __builtin_amdgcn_mfma_f32_16x16x32_bf16(WF[_m], FA, acc[_m][0], 0, 0, 0); \
            acc[_m][1] = __builtin_amdgcn_mfma_f32_16x16x32_bf16(WF[_m], FB, acc[_m][1], 0, 0, 0); \
        }                                                                   \
    }

    // ---- prologue: X chunk 0 + W chunk 0 in flight ----
    XLOAD(P0, P1, 0);
    WLOAD(WE, 0);

    for (int kc2 = 0; kc2 < nkc; kc2 += 2) {
        bf16x8 fA, fB;

        // even chunk kc2: compute from P/WE; prefetch kc2+1 into Q/WO
        XLOAD(Q0, Q1, kc2 + 1);
        WLOAD(WO, kc2 + 1);
        CVT(P0, fA);
        CVT(P1, fB);
        MFMA18(WE, fA, fB);

        // odd chunk kc2+1: compute from Q/WO; prefetch kc2+2 into P/WE
        if (kc2 + 2 < nkc) {
            XLOAD(P0, P1, kc2 + 2);
            WLOAD(WE, kc2 + 2);
        }
        CVT(Q0, fA);
        CVT(Q1, fB);
        MFMA18(WO, fA, fB);
    }

#undef MFMA18
#undef CVT
#undef WLOAD
#undef XLOAD

    // ---- epilogue: in-register DFL decode + store ----
    // D layout (m89): value[r] = D[mtile*16 + q4*4 + r][col]
    float4 bcv[5];
#pragma unroll
    for (int m = 0; m < 5; ++m)
        bcv[m] = *(const float4*)(bcls + m * 16 + q4 * 4);

    const float LOG2E = 1.44269504088896f;

#pragma unroll
    for (int nf = 0; nf < 2; ++nf) {
        const int alocal = wv * 32 + nf * 16 + col;
        const int hw = hw0 + alocal;

        float dist[4];
#pragma unroll
        for (int g = 0; g < 4; ++g) {
            const float4 bbv = *(const float4*)(bbox + g * 16 + q4 * 4);
            const float v0 = acc[g][nf][0] + bbv.x;
            const float v1 = acc[g][nf][1] + bbv.y;
            const float v2 = acc[g][nf][2] + bbv.z;
            const float v3 = acc[g][nf][3] + bbv.w;
            // softmax over 16 bins: 4 regs x 4 lanes (col, col+16, col+32, col+48)
            float mx = fmaxf(fmaxf(v0, v1), fmaxf(v2, v3));
            mx = fmaxf(mx, __shfl_xor(mx, 16));
            mx = fmaxf(mx, __shfl_xor(mx, 32));
            const float e0 = __builtin_amdgcn_exp2f((v0 - mx) * LOG2E);
            const float e1 = __builtin_amdgcn_exp2f((v1 - mx) * LOG2E);
            const float e2 = __builtin_amdgcn_exp2f((v2 - mx) * LOG2E);
            const float e3 = __builtin_amdgcn_exp2f((v3 - mx) * LOG2E);
            float s  = e0 + e1 + e2 + e3;
            float ws = e1 + 2.f * e2 + 3.f * e3 + (float)(q4 * 4) * s;
            s  += __shfl_xor(s, 16);
            s  += __shfl_xor(s, 32);
            ws += __shfl_xor(ws, 16);
            ws += __shfl_xor(ws, 32);
            dist[g] = ws / s;
        }

        const size_t obase = ((size_t)b * 8400 + AOFF + hw) * 84;
        if (q4 == 0) {
            const float ax = (float)(hw % GW) + 0.5f;
            const float ay = (float)(hw / GW) + 0.5f;
            f32x4 bx;
            bx[0] = (ax + 0.5f * (dist[2] - dist[0])) * STRIDE;
            bx[1] = (ay + 0.5f * (dist[3] - dist[1])) * STRIDE;
            bx[2] = (dist[0] + dist[2]) * STRIDE;
            bx[3] = (dist[1] + dist[3]) * STRIDE;
            *(f32x4*)(out + obase) = bx;
        }
#pragma unroll
        for (int m = 0; m < 5; ++m) {
            f32x4 v;
            v[0] = acc[m + 4][nf][0] + bcv[m].x;
            v[1] = acc[m + 4][nf][1] + bcv[m].y;
            v[2] = acc[m + 4][nf][2] + bcv[m].z;
            v[3] = acc[m + 4][nf][3] + bcv[m].w;
            *(f32x4*)(out + obase + 4 + m * 16 + q4 * 4) = v;
        }
    }
}

extern "C" void kernel_launch(void* const* d_in, const int* in_sizes, int n_in,
                              void* d_out, int out_size, void* d_ws, size_t ws_size,
                              hipStream_t stream) {
    const float* x0  = (const float*)d_in[0];
    const float* x1  = (const float*)d_in[1];
    const float* x2  = (const float*)d_in[2];
    const float* wb0 = (const float*)d_in[3];
    const float* bb0 = (const float*)d_in[4];
    const float* wc0 = (const float*)d_in[5];
    const float* bc0 = (const float*)d_in[6];
    const float* wb1 = (const float*)d_in[7];
    const float* bb1 = (const float*)d_in[8];
    const float* wc1 = (const float*)d_in[9];
    const float* bc1 = (const float*)d_in[10];
    const float* wb2 = (const float*)d_in[11];
    const float* bb2 = (const float*)d_in[12];
    const float* wc2 = (const float*)d_in[13];
    const float* bc2 = (const float*)d_in[14];

    unsigned char* wimg = (unsigned char*)d_ws;

    prep_w_kernel<<<90, 256, 0, stream>>>(wb0, wc0, wb1, wc1, wb2, wc2, wimg);

    UltralyticsDetect_kernel<<<1072, NTHREADS, 0, stream>>>(
        x0, x1, x2, wimg,
        bb0, bc0, bb1, bc1, bb2, bc2,
        (float*)d_out);
}

// Round 13
// 63.900 us; speedup vs baseline: 2.0350x; 2.0350x over previous
//
#include <hip/hip_runtime.h>

// UltralyticsDetect head, fused: per-level 1x1-conv GEMM (M=144, K=C, N=B*HW)
// in bf16 MFMA + in-register DFL softmax decode + output assembly.
// Output: (16, 8400, 84) f32.
//
// R13: PERSISTENT SINGLE-ROUND grid. 768 blocks (3/CU exactly); each block
// owns a static tile list (208 L1 + 64 L2 singles; 304 L0 pairs + 192 L0
// singles -> makespan 2 units, 87% packing vs 71% at 1.4 rounds). Tile body
// is R9's (best known: X async-DMA+swizzle staged, W pre-swizzled DMA).
// XCD-bijective block swizzle groups same-level blocks per XCD (W L2-hot).
// Tile-2 prologue DMA overlaps tile-1 epilogue stores.

typedef __bf16 bf16x8 __attribute__((ext_vector_type(8)));
typedef float  f32x4  __attribute__((ext_vector_type(4)));

#define NTHREADS 256

// W image in d_ws: per level, C/32 chunks of 144 rows * 64 B, pre-swizzled.
#define WCHUNK 9216              // 144 * 64 B
#define WOFF0 0
#define WOFF1 73728              // level0: 8 chunks
#define WOFF2 221184             // level1: 16 chunks ; level2: 16 chunks after

#define XBUF 16384               // 32 rows * 512 B (128 anchors f32)

// round-half-up f32 -> bf16, pack two into one u32 (a -> low16, b -> high16)
__device__ __forceinline__ unsigned int pack_bf16(float a, float b) {
    unsigned int ua = __builtin_bit_cast(unsigned int, a);
    unsigned int ub = __builtin_bit_cast(unsigned int, b);
    return ((ua + 0x8000u) >> 16) | ((ub + 0x8000u) & 0xffff0000u);
}

// W LDS tile: [144 rows][32 bf16] = 64B rows, 16B-slot swizzle.
__device__ __forceinline__ int swz32(int row, int kbyte) {
    return row * 64 + (kbyte ^ ((((row & 3) ^ ((row >> 2) & 1))) << 4));
}

// async global->LDS, 16B per lane
__device__ __forceinline__ void gload_lds16(const void* g, void* l) {
    __builtin_amdgcn_global_load_lds(
        (const __attribute__((address_space(1))) void*)g,
        (__attribute__((address_space(3))) void*)l, 16, 0, 0);
}

// ---------------- prep kernel: W f32 -> bf16, pre-swizzled into d_ws --------
__global__ __launch_bounds__(256)
void prep_w_kernel(const float* __restrict__ wb0, const float* __restrict__ wc0,
                   const float* __restrict__ wb1, const float* __restrict__ wc1,
                   const float* __restrict__ wb2, const float* __restrict__ wc2,
                   unsigned char* __restrict__ ws) {
    int uid = blockIdx.x * 256 + threadIdx.x;   // one unit = 8 k-elems
    if (uid >= 23040) return;                   // 4608 + 9216 + 9216
    const float* wb; const float* wc; int C; size_t off; int uu;
    if (uid < 4608)       { wb = wb0; wc = wc0; C = 256; off = WOFF0; uu = uid; }
    else if (uid < 13824) { wb = wb1; wc = wc1; C = 512; off = WOFF1; uu = uid - 4608; }
    else                  { wb = wb2; wc = wc2; C = 512; off = WOFF2; uu = uid - 13824; }
    const int kunits = C / 8;
    const int row = uu / kunits;
    const int k   = (uu % kunits) * 8;
    const float* src = ((row < 64) ? (wb + row * C) : (wc + (row - 64) * C)) + k;
    const float4 f0 = *(const float4*)(src);
    const float4 f1 = *(const float4*)(src + 4);
    uint4 p;
    p.x = pack_bf16(f0.x, f0.y);
    p.y = pack_bf16(f0.z, f0.w);
    p.z = pack_bf16(f1.x, f1.y);
    p.w = pack_bf16(f1.z, f1.w);
    const int chunk = k >> 5;            // 32-k chunks
    const int kg    = (k & 31) >> 3;     // 16B slot within row
    *(uint4*)(ws + off + (size_t)chunk * WCHUNK + swz32(row, kg * 16)) = p;
}

// ---------------- per-tile body (R9's, verbatim) ----------------------------
template <int LVL>
__device__ __forceinline__ void run_tile(
        int rb,
        const float* __restrict__ x,
        const unsigned char* __restrict__ wimg_all,
        const float* __restrict__ bbox, const float* __restrict__ bcls,
        float* __restrict__ out,
        unsigned char* s_w, unsigned char* s_x) {

    constexpr int    C      = (LVL == 0) ? 256 : 512;
    constexpr int    GW     = (LVL == 0) ? 80 : (LVL == 1 ? 40 : 20);
    constexpr int    HW     = GW * GW;
    constexpr int    AOFF   = (LVL == 0) ? 0 : (LVL == 1 ? 6400 : 8000);
    constexpr float  STRIDE = (LVL == 0) ? 8.0f : (LVL == 1 ? 16.0f : 32.0f);
    constexpr int    TPB    = (HW + 127) / 128;  // 128-anchor tiles per image
    constexpr size_t WOFF   = (LVL == 0) ? WOFF0 : (LVL == 1 ? WOFF1 : WOFF2);
    const int nkc = C / 32;

    const int b    = rb / TPB;
    const int tile = rb % TPB;
    int hw0 = tile * 128;
    if (hw0 > HW - 128) hw0 = HW - 128;   // tail tiles overlap previous tile

    const int tid  = threadIdx.x;
    const int wv   = tid >> 6;        // wave 0..3
    const int lane = tid & 63;
    const int col  = lane & 15;       // MFMA n/col lane
    const int q4   = lane >> 4;       // MFMA row-quarter

    const float* xlev = x + (size_t)b * C * HW;
    const unsigned char* wimg = wimg_all + WOFF;

    // X DMA: wave wv stages rows wv*8..wv*8+7 (4 instr x 2 rows). Source
    // anchor-group pre-permuted by wv so swizzled reads see linear data.
    const int xg  = (((lane & 31) ^ (wv << 2)) << 2);  // anchor offset (4/grp)
    const int xr  = lane >> 5;                          // row parity
    // X frag read bases: byte = r*512 + ((a<<2) ^ (q4<<6)), a = wv*32+f*16+col
    const int xrd0 = (((wv * 32 + col) << 2) ^ (q4 << 6)) + q4 * 8 * 512;
    const int xrd1 = (((wv * 32 + 16 + col) << 2) ^ (q4 << 6)) + q4 * 8 * 512;

    f32x4 acc[9][2];
#pragma unroll
    for (int m = 0; m < 9; ++m) {
        acc[m][0] = (f32x4){0.f, 0.f, 0.f, 0.f};
        acc[m][1] = (f32x4){0.f, 0.f, 0.f, 0.f};
    }

#define XDMA(CC, BUF)                                                       \
    {                                                                       \
        _Pragma("unroll")                                                   \
        for (int _i = 0; _i < 4; ++_i) {                                    \
            const int _r2 = wv * 8 + _i * 2;                                \
            gload_lds16(xlev + (size_t)((CC) * 32 + _r2 + xr) * HW + hw0 + xg, \
                        s_x + (BUF) * XBUF + _r2 * 512);                    \
        }                                                                   \
    }

#define WDMA(CC, BUF)                                                       \
    {                                                                       \
        _Pragma("unroll")                                                   \
        for (int _i = 0; _i < 3; ++_i) {                                    \
            const int _u = tid + _i * 256;                                  \
            if (_u < 576)                                                   \
                gload_lds16(wimg + (size_t)(CC) * WCHUNK + _u * 16,         \
                            s_w + (BUF) * WCHUNK + _u * 16);                \
        }                                                                   \
    }

    // ---- prologue: stage chunk 0 ----
    XDMA(0, 0);
    WDMA(0, 0);
    __builtin_amdgcn_sched_barrier(0);
    asm volatile("s_waitcnt vmcnt(0)" ::: "memory");
    __builtin_amdgcn_s_barrier();
    __builtin_amdgcn_sched_barrier(0);

    for (int kc = 0; kc < nkc; ++kc) {
        const int cur = kc & 1;
        const bool more = (kc + 1 < nkc);

        if (more) {                      // issue next chunk's DMAs first
            XDMA(kc + 1, cur ^ 1);
            WDMA(kc + 1, cur ^ 1);
        }
        __builtin_amdgcn_sched_barrier(0);

        // ---- X fragments from LDS (swizzled, 2-way-free) + convert ----
        const unsigned char* xbuf = s_x + cur * XBUF;
        float xf0[8], xf1[8];
#pragma unroll
        for (int j = 0; j < 8; ++j) {
            xf0[j] = *(const float*)(xbuf + xrd0 + j * 512);
            xf1[j] = *(const float*)(xbuf + xrd1 + j * 512);
        }
        uint4 qa, qb;
        qa.x = pack_bf16(xf0[0], xf0[1]); qa.y = pack_bf16(xf0[2], xf0[3]);
        qa.z = pack_bf16(xf0[4], xf0[5]); qa.w = pack_bf16(xf0[6], xf0[7]);
        qb.x = pack_bf16(xf1[0], xf1[1]); qb.y = pack_bf16(xf1[2], xf1[3]);
        qb.z = pack_bf16(xf1[4], xf1[5]); qb.w = pack_bf16(xf1[6], xf1[7]);
        const bf16x8 fA = __builtin_bit_cast(bf16x8, qa);
        const bf16x8 fB = __builtin_bit_cast(bf16x8, qb);

        // ---- MFMA: 9 M-tiles x 2 N-frags; one A-read feeds 2 MFMAs ----
        const unsigned char* wbuf = s_w + cur * WCHUNK;
#pragma unroll
        for (int m = 0; m < 9; ++m) {
            const bf16x8 a_ = *(const bf16x8*)(wbuf + swz32(m * 16 + col, q4 * 16));
            acc[m][0] = __builtin_amdgcn_mfma_f32_16x16x32_bf16(a_, fA, acc[m][0], 0, 0, 0);
            acc[m][1] = __builtin_amdgcn_mfma_f32_16x16x32_bf16(a_, fB, acc[m][1], 0, 0, 0);
        }
        __builtin_amdgcn_sched_barrier(0);

        if (more) {
            asm volatile("s_waitcnt vmcnt(0)" ::: "memory");
            __builtin_amdgcn_s_barrier();
            __builtin_amdgcn_sched_barrier(0);
        }
    }

#undef WDMA
#undef XDMA

    // ---- epilogue: in-register DFL decode + store ----
    // D layout (m89): value[r] = D[mtile*16 + q4*4 + r][col]
    float4 bcv[5];
#pragma unroll
    for (int m = 0; m < 5; ++m)
        bcv[m] = *(const float4*)(bcls + m * 16 + q4 * 4);

    const float LOG2E = 1.44269504088896f;

#pragma unroll
    for (int nf = 0; nf < 2; ++nf) {
        const int alocal = wv * 32 + nf * 16 + col;
        const int hw = hw0 + alocal;

        float dist[4];
#pragma unroll
        for (int g = 0; g < 4; ++g) {
            const float4 bbv = *(const float4*)(bbox + g * 16 + q4 * 4);
            const float v0 = acc[g][nf][0] + bbv.x;
            const float v1 = acc[g][nf][1] + bbv.y;
            const float v2 = acc[g][nf][2] + bbv.z;
            const float v3 = acc[g][nf][3] + bbv.w;
            // softmax over 16 bins: 4 regs x 4 lanes (col, col+16, col+32, col+48)
            float mx = fmaxf(fmaxf(v0, v1), fmaxf(v2, v3));
            mx = fmaxf(mx, __shfl_xor(mx, 16));
            mx = fmaxf(mx, __shfl_xor(mx, 32));
            const float e0 = __builtin_amdgcn_exp2f((v0 - mx) * LOG2E);
            const float e1 = __builtin_amdgcn_exp2f((v1 - mx) * LOG2E);
            const float e2 = __builtin_amdgcn_exp2f((v2 - mx) * LOG2E);
            const float e3 = __builtin_amdgcn_exp2f((v3 - mx) * LOG2E);
            float s  = e0 + e1 + e2 + e3;
            float ws = e1 + 2.f * e2 + 3.f * e3 + (float)(q4 * 4) * s;
            s  += __shfl_xor(s, 16);
            s  += __shfl_xor(s, 32);
            ws += __shfl_xor(ws, 16);
            ws += __shfl_xor(ws, 32);
            dist[g] = ws / s;
        }

        const size_t obase = ((size_t)b * 8400 + AOFF + hw) * 84;
        if (q4 == 0) {
            const float ax = (float)(hw % GW) + 0.5f;
            const float ay = (float)(hw / GW) + 0.5f;
            f32x4 bx;
            bx[0] = (ax + 0.5f * (dist[2] - dist[0])) * STRIDE;
            bx[1] = (ay + 0.5f * (dist[3] - dist[1])) * STRIDE;
            bx[2] = (dist[0] + dist[2]) * STRIDE;
            bx[3] = (dist[1] + dist[3]) * STRIDE;
            *(f32x4*)(out + obase) = bx;
        }
#pragma unroll
        for (int m = 0; m < 5; ++m) {
            f32x4 v;
            v[0] = acc[m + 4][nf][0] + bcv[m].x;
            v[1] = acc[m + 4][nf][1] + bcv[m].y;
            v[2] = acc[m + 4][nf][2] + bcv[m].z;
            v[3] = acc[m + 4][nf][3] + bcv[m].w;
            *(f32x4*)(out + obase + 4 + m * 16 + q4 * 4) = v;
        }
    }
}

// ---------------- main kernel: persistent tile lists ------------------------
__global__ __launch_bounds__(NTHREADS, 3)
void UltralyticsDetect_kernel(
        const float* __restrict__ x0, const float* __restrict__ x1, const float* __restrict__ x2,
        const unsigned char* __restrict__ wimg,
        const float* __restrict__ bb0, const float* __restrict__ bc0,
        const float* __restrict__ bb1, const float* __restrict__ bc1,
        const float* __restrict__ bb2, const float* __restrict__ bc2,
        float* __restrict__ out) {

    __shared__ __align__(16) unsigned char s_w[2 * WCHUNK];  // 18 KiB dbuf
    __shared__ __align__(16) unsigned char s_x[2 * XBUF];    // 32 KiB dbuf

    // XCD-bijective swizzle: 96 consecutive g per XCD -> same-level blocks
    // share one W image in their XCD's L2.
    const int bid = blockIdx.x;                  // grid = 768 exactly
    const int g   = (bid & 7) * 96 + (bid >> 3); // bijective on [0,768)

    // Tile lists: g<208 -> L1 single; g<272 -> L2 single;
    // else L0: h<304 -> pair {2h, 2h+1}; h>=304 -> single {608+h-304}.
    if (g < 208) {
        run_tile<1>(g, x1, wimg, bb1, bc1, out, s_w, s_x);
    } else if (g < 272) {
        run_tile<2>(g - 208, x2, wimg, bb2, bc2, out, s_w, s_x);
    } else {
        const int h = g - 272;
        if (h < 304) {
            run_tile<0>(2 * h,     x0, wimg, bb0, bc0, out, s_w, s_x);
            run_tile<0>(2 * h + 1, x0, wimg, bb0, bc0, out, s_w, s_x);
        } else {
            run_tile<0>(608 + (h - 304), x0, wimg, bb0, bc0, out, s_w, s_x);
        }
    }
}

extern "C" void kernel_launch(void* const* d_in, const int* in_sizes, int n_in,
                              void* d_out, int out_size, void* d_ws, size_t ws_size,
                              hipStream_t stream) {
    const float* x0  = (const float*)d_in[0];
    const float* x1  = (const float*)d_in[1];
    const float* x2  = (const float*)d_in[2];
    const float* wb0 = (const float*)d_in[3];
    const float* bb0 = (const float*)d_in[4];
    const float* wc0 = (const float*)d_in[5];
    const float* bc0 = (const float*)d_in[6];
    const float* wb1 = (const float*)d_in[7];
    const float* bb1 = (const float*)d_in[8];
    const float* wc1 = (const float*)d_in[9];
    const float* bc1 = (const float*)d_in[10];
    const float* wb2 = (const float*)d_in[11];
    const float* bb2 = (const float*)d_in[12];
    const float* wc2 = (const float*)d_in[13];
    const float* bc2 = (const float*)d_in[14];

    unsigned char* wimg = (unsigned char*)d_ws;

    prep_w_kernel<<<90, 256, 0, stream>>>(wb0, wc0, wb1, wc1, wb2, wc2, wimg);

    UltralyticsDetect_kernel<<<768, NTHREADS, 0, stream>>>(
        x0, x1, x2, wimg,
        bb0, bc0, bb1, bc1, bb2, bc2,
        (float*)d_out);
}

// Round 14
// 54.479 us; speedup vs baseline: 2.3870x; 1.1729x over previous
//
#include <hip/hip_runtime.h>

// UltralyticsDetect head, fused: per-level 1x1-conv GEMM (M=144, K=C, N=B*HW)
// in bf16 MFMA + in-register DFL softmax decode + output assembly.
// Output: (16, 8400, 84) f32.
//
// R14: byte-reduction round. 512-thread blocks / 256 anchors (8 waves x 32):
// blocks 1072->544 so the per-block W re-stage (the only redundant traffic,
// ~99 MB delivered) halves to ~50 MB. X staged bf16 reg-staged (T14):
// thin coalesced f32 loads -> pack -> ds_write [anchor][k]-major; in-loop X
// frag read becomes 2x ds_read_b128 and CVT leaves the loop. LDS 50 KB,
// VGPR ~110 -> 2 blocks/CU (16 waves). One __syncthreads per iteration.

typedef __bf16 bf16x8 __attribute__((ext_vector_type(8)));
typedef float  f32x4  __attribute__((ext_vector_type(4)));

#define NTHREADS 512

// W image in d_ws: per level, C/32 chunks of 144 rows * 64 B, pre-swizzled.
#define WCHUNK 9216              // 144 * 64 B
#define WOFF0 0
#define WOFF1 73728              // level0: 8 chunks
#define WOFF2 221184             // level1: 16 chunks ; level2: 16 chunks after

#define XBUF 16384               // 256 anchors * 64 B (32 k bf16)

// round-half-up f32 -> bf16, pack two into one u32 (a -> low16, b -> high16)
__device__ __forceinline__ unsigned int pack_bf16(float a, float b) {
    unsigned int ua = __builtin_bit_cast(unsigned int, a);
    unsigned int ub = __builtin_bit_cast(unsigned int, b);
    return ((ua + 0x8000u) >> 16) | ((ub + 0x8000u) & 0xffff0000u);
}

// 64-B-row LDS tile ([row][32 bf16]), 16B-slot swizzle (proven R7-R13).
__device__ __forceinline__ int swz32(int row, int kbyte) {
    return row * 64 + (kbyte ^ ((((row & 3) ^ ((row >> 2) & 1))) << 4));
}

// async global->LDS, 16B per lane
__device__ __forceinline__ void gload_lds16(const void* g, void* l) {
    __builtin_amdgcn_global_load_lds(
        (const __attribute__((address_space(1))) void*)g,
        (__attribute__((address_space(3))) void*)l, 16, 0, 0);
}

// ---------------- prep kernel: W f32 -> bf16, pre-swizzled into d_ws --------
__global__ __launch_bounds__(256)
void prep_w_kernel(const float* __restrict__ wb0, const float* __restrict__ wc0,
                   const float* __restrict__ wb1, const float* __restrict__ wc1,
                   const float* __restrict__ wb2, const float* __restrict__ wc2,
                   unsigned char* __restrict__ ws) {
    int uid = blockIdx.x * 256 + threadIdx.x;   // one unit = 8 k-elems
    if (uid >= 23040) return;                   // 4608 + 9216 + 9216
    const float* wb; const float* wc; int C; size_t off; int uu;
    if (uid < 4608)       { wb = wb0; wc = wc0; C = 256; off = WOFF0; uu = uid; }
    else if (uid < 13824) { wb = wb1; wc = wc1; C = 512; off = WOFF1; uu = uid - 4608; }
    else                  { wb = wb2; wc = wc2; C = 512; off = WOFF2; uu = uid - 13824; }
    const int kunits = C / 8;
    const int row = uu / kunits;
    const int k   = (uu % kunits) * 8;
    const float* src = ((row < 64) ? (wb + row * C) : (wc + (row - 64) * C)) + k;
    const float4 f0 = *(const float4*)(src);
    const float4 f1 = *(const float4*)(src + 4);
    uint4 p;
    p.x = pack_bf16(f0.x, f0.y);
    p.y = pack_bf16(f0.z, f0.w);
    p.z = pack_bf16(f1.x, f1.y);
    p.w = pack_bf16(f1.z, f1.w);
    const int chunk = k >> 5;            // 32-k chunks
    const int kg    = (k & 31) >> 3;     // 16B slot within row
    *(uint4*)(ws + off + (size_t)chunk * WCHUNK + swz32(row, kg * 16)) = p;
}

// ---------------- main kernel ----------------------------------------------
__global__ __launch_bounds__(NTHREADS, 4)
void UltralyticsDetect_kernel(
        const float* __restrict__ x0, const float* __restrict__ x1, const float* __restrict__ x2,
        const unsigned char* __restrict__ wimg,
        const float* __restrict__ bb0, const float* __restrict__ bc0,
        const float* __restrict__ bb1, const float* __restrict__ bc1,
        const float* __restrict__ bb2, const float* __restrict__ bc2,
        float* __restrict__ out) {

    __shared__ __align__(16) unsigned char s_w[2 * WCHUNK];  // 18 KiB dbuf
    __shared__ __align__(16) unsigned char s_x[2 * XBUF];    // 32 KiB dbuf (bf16)

    // ---- runtime level decode (long levels first) ----
    // L1: 16 b * 7 tiles = 112 ; L2: 16*2 = 32 ; L0: 16*25 = 400 -> 544 blocks
    const int bid = blockIdx.x;
    const float* x; const float* bbox; const float* bcls;
    int C, GW, HW, AOFF, TPB, rb; float STRIDE; size_t WOFF;
    if (bid < 112) {
        x = x1; bbox = bb1; bcls = bc1; rb = bid;
        C = 512; GW = 40; HW = 1600; AOFF = 6400; TPB = 7;  STRIDE = 16.0f; WOFF = WOFF1;
    } else if (bid < 144) {
        x = x2; bbox = bb2; bcls = bc2; rb = bid - 112;
        C = 512; GW = 20; HW = 400;  AOFF = 8000; TPB = 2;  STRIDE = 32.0f; WOFF = WOFF2;
    } else {
        x = x0; bbox = bb0; bcls = bc0; rb = bid - 144;
        C = 256; GW = 80; HW = 6400; AOFF = 0;    TPB = 25; STRIDE = 8.0f;  WOFF = WOFF0;
    }
    const int nkc = C / 32;

    const int b    = rb / TPB;
    const int tile = rb - b * TPB;
    int hw0 = tile * 256;
    if (hw0 > HW - 256) hw0 = HW - 256;   // tail tiles overlap previous tile

    const int tid  = threadIdx.x;
    const int wv   = tid >> 6;        // wave 0..7
    const int lane = tid & 63;
    const int col  = lane & 15;       // MFMA n/col lane
    const int q4   = lane >> 4;       // MFMA row-quarter

    const float* xlev = x + (size_t)b * C * HW;
    const unsigned char* wlev = wimg + WOFF;

    // X staging: thread -> (anchor sa, k-half sg). One anchor, 16 k each.
    const int sa = (wv & 3) * 64 + lane;   // 0..255
    const int sg = wv >> 2;                // 0..1
    const float* xsrc = xlev + hw0 + sa;   // + (k)*HW walks k
    // staging write addrs (two 16B slots in row sa)
    const int swzb  = (((sa & 3) ^ ((sa >> 2) & 1))) << 4;
    const int xw0   = sa * 64 + ((sg * 32) ^ swzb);
    const int xw1   = sa * 64 + ((sg * 32 + 16) ^ swzb);

    // frag anchors
    const int a0 = wv * 32 + col;
    const int a1 = a0 + 16;
    const int xr0 = swz32(a0, q4 * 16);
    const int xr1 = swz32(a1, q4 * 16);

    f32x4 acc[9][2];
#pragma unroll
    for (int m = 0; m < 9; ++m) {
        acc[m][0] = (f32x4){0.f, 0.f, 0.f, 0.f};
        acc[m][1] = (f32x4){0.f, 0.f, 0.f, 0.f};
    }

    float S[16];   // X stage regs: 16 k values of anchor sa (static-indexed)

#define XLOADS(CC)                                                          \
    {                                                                       \
        const float* _p = xsrc + (size_t)((CC) * 32 + sg * 16) * HW;        \
        _Pragma("unroll")                                                   \
        for (int _m = 0; _m < 16; ++_m)                                     \
            S[_m] = _p[(size_t)_m * HW];                                    \
    }

#define XWRITE(BUF)                                                         \
    {                                                                       \
        uint4 _w0, _w1;                                                     \
        _w0.x = pack_bf16(S[0],  S[1]);  _w0.y = pack_bf16(S[2],  S[3]);    \
        _w0.z = pack_bf16(S[4],  S[5]);  _w0.w = pack_bf16(S[6],  S[7]);    \
        _w1.x = pack_bf16(S[8],  S[9]);  _w1.y = pack_bf16(S[10], S[11]);   \
        _w1.z = pack_bf16(S[12], S[13]); _w1.w = pack_bf16(S[14], S[15]);   \
        *(uint4*)(s_x + (BUF) * XBUF + xw0) = _w0;                          \
        *(uint4*)(s_x + (BUF) * XBUF + xw1) = _w1;                          \
    }

#define WDMA(CC, BUF)                                                       \
    {                                                                       \
        gload_lds16(wlev + (size_t)(CC) * WCHUNK + tid * 16,                \
                    s_w + (BUF) * WCHUNK + tid * 16);                       \
        if (tid < 64)                                                       \
            gload_lds16(wlev + (size_t)(CC) * WCHUNK + (512 + tid) * 16,    \
                        s_w + (BUF) * WCHUNK + (512 + tid) * 16);           \
    }

    // ---- prologue ----
    XLOADS(0);
    XWRITE(0);          // auto vmcnt wait on S
    WDMA(0, 0);
    XLOADS(1);
    __syncthreads();    // drains WDMA(0) (+S(1), acceptable)

    for (int kc = 0; kc < nkc; ++kc) {
        const int buf = kc & 1;

        if (kc + 1 < nkc) {
            XWRITE(buf ^ 1);        // packs S = X(kc+1), writes other buffer
            WDMA(kc + 1, buf ^ 1);  // W(kc+1) flies through the MFMA phase
        }
        if (kc + 2 < nkc) XLOADS(kc + 2);

        // ---- X fragments: 2x ds_read_b128, bf16, no CVT ----
        const bf16x8 fA = *(const bf16x8*)(s_x + buf * XBUF + xr0);
        const bf16x8 fB = *(const bf16x8*)(s_x + buf * XBUF + xr1);

        // ---- MFMA: 9 M-tiles x 2 N-frags ----
        const unsigned char* wbuf = s_w + buf * WCHUNK;
#pragma unroll
        for (int m = 0; m < 9; ++m) {
            const bf16x8 a_ = *(const bf16x8*)(wbuf + swz32(m * 16 + col, q4 * 16));
            acc[m][0] = __builtin_amdgcn_mfma_f32_16x16x32_bf16(a_, fA, acc[m][0], 0, 0, 0);
            acc[m][1] = __builtin_amdgcn_mfma_f32_16x16x32_bf16(a_, fB, acc[m][1], 0, 0, 0);
        }

        __syncthreads();   // seals LDS reads; drains next chunk's DMAs/writes
    }

#undef WDMA
#undef XWRITE
#undef XLOADS

    // ---- epilogue: in-register DFL decode + store ----
    // D layout (m89): value[r] = D[mtile*16 + q4*4 + r][col]
    float4 bcv[5];
#pragma unroll
    for (int m = 0; m < 5; ++m)
        bcv[m] = *(const float4*)(bcls + m * 16 + q4 * 4);

    const float LOG2E = 1.44269504088896f;

#pragma unroll
    for (int nf = 0; nf < 2; ++nf) {
        const int alocal = wv * 32 + nf * 16 + col;
        const int hw = hw0 + alocal;

        float dist[4];
#pragma unroll
        for (int g = 0; g < 4; ++g) {
            const float4 bbv = *(const float4*)(bbox + g * 16 + q4 * 4);
            const float v0 = acc[g][nf][0] + bbv.x;
            const float v1 = acc[g][nf][1] + bbv.y;
            const float v2 = acc[g][nf][2] + bbv.z;
            const float v3 = acc[g][nf][3] + bbv.w;
            // softmax over 16 bins: 4 regs x 4 lanes (col, col+16, col+32, col+48)
            float mx = fmaxf(fmaxf(v0, v1), fmaxf(v2, v3));
            mx = fmaxf(mx, __shfl_xor(mx, 16));
            mx = fmaxf(mx, __shfl_xor(mx, 32));
            const float e0 = __builtin_amdgcn_exp2f((v0 - mx) * LOG2E);
            const float e1 = __builtin_amdgcn_exp2f((v1 - mx) * LOG2E);
            const float e2 = __builtin_amdgcn_exp2f((v2 - mx) * LOG2E);
            const float e3 = __builtin_amdgcn_exp2f((v3 - mx) * LOG2E);
            float s  = e0 + e1 + e2 + e3;
            float ws = e1 + 2.f * e2 + 3.f * e3 + (float)(q4 * 4) * s;
            s  += __shfl_xor(s, 16);
            s  += __shfl_xor(s, 32);
            ws += __shfl_xor(ws, 16);
            ws += __shfl_xor(ws, 32);
            dist[g] = ws / s;
        }

        const size_t obase = ((size_t)b * 8400 + AOFF + hw) * 84;
        if (q4 == 0) {
            const float ax = (float)(hw % GW) + 0.5f;
            const float ay = (float)(hw / GW) + 0.5f;
            f32x4 bx;
            bx[0] = (ax + 0.5f * (dist[2] - dist[0])) * STRIDE;
            bx[1] = (ay + 0.5f * (dist[3] - dist[1])) * STRIDE;
            bx[2] = (dist[0] + dist[2]) * STRIDE;
            bx[3] = (dist[1] + dist[3]) * STRIDE;
            *(f32x4*)(out + obase) = bx;
        }
#pragma unroll
        for (int m = 0; m < 5; ++m) {
            f32x4 v;
            v[0] = acc[m + 4][nf][0] + bcv[m].x;
            v[1] = acc[m + 4][nf][1] + bcv[m].y;
            v[2] = acc[m + 4][nf][2] + bcv[m].z;
            v[3] = acc[m + 4][nf][3] + bcv[m].w;
            *(f32x4*)(out + obase + 4 + m * 16 + q4 * 4) = v;
        }
    }
}

extern "C" void kernel_launch(void* const* d_in, const int* in_sizes, int n_in,
                              void* d_out, int out_size, void* d_ws, size_t ws_size,
                              hipStream_t stream) {
    const float* x0  = (const float*)d_in[0];
    const float* x1  = (const float*)d_in[1];
    const float* x2  = (const float*)d_in[2];
    const float* wb0 = (const float*)d_in[3];
    const float* bb0 = (const float*)d_in[4];
    const float* wc0 = (const float*)d_in[5];
    const float* bc0 = (const float*)d_in[6];
    const float* wb1 = (const float*)d_in[7];
    const float* bb1 = (const float*)d_in[8];
    const float* wc1 = (const float*)d_in[9];
    const float* bc1 = (const float*)d_in[10];
    const float* wb2 = (const float*)d_in[11];
    const float* bb2 = (const float*)d_in[12];
    const float* wc2 = (const float*)d_in[13];
    const float* bc2 = (const float*)d_in[14];

    unsigned char* wimg = (unsigned char*)d_ws;

    prep_w_kernel<<<90, 256, 0, stream>>>(wb0, wc0, wb1, wc1, wb2, wc2, wimg);

    UltralyticsDetect_kernel<<<544, NTHREADS, 0, stream>>>(
        x0, x1, x2, wimg,
        bb0, bc0, bb1, bc1, bb2, bc2,
        (float*)d_out);
}

// Round 15
// 48.278 us; speedup vs baseline: 2.6936x; 1.1284x over previous
//
#include <hip/hip_runtime.h>

// UltralyticsDetect head, fused: per-level 1x1-conv GEMM (M=144, K=C, N=B*HW)
// in bf16 MFMA + in-register DFL softmax decode + output assembly.
// Output: (16, 8400, 84) f32.
//
// R15 = R9 restored verbatim (best measured: 48.3 us). Ledger of falsified
// alternatives (R10-R14): counted-vmcnt triple-buffer (null), W-from-global
// (worse: exposed L2 latency), all-register (spill), persistent packed grid
// (worse), 256-anchor byte-reduction (worse). The op is pinned at the
// streaming floor of its access pattern: X read once as 512B-granular
// k-strided segments (no inter-block reuse) + 45 MB output.

typedef __bf16 bf16x8 __attribute__((ext_vector_type(8)));
typedef float  f32x4  __attribute__((ext_vector_type(4)));

#define NTHREADS 256

// W image in d_ws: per level, C/32 chunks of 144 rows * 64 B, pre-swizzled.
#define WCHUNK 9216              // 144 * 64 B
#define WOFF0 0
#define WOFF1 73728              // level0: 8 chunks
#define WOFF2 221184             // level1: 16 chunks ; level2: 16 chunks after

#define XBUF 16384               // 32 rows * 512 B (128 anchors f32)

// round-half-up f32 -> bf16, pack two into one u32 (a -> low16, b -> high16)
__device__ __forceinline__ unsigned int pack_bf16(float a, float b) {
    unsigned int ua = __builtin_bit_cast(unsigned int, a);
    unsigned int ub = __builtin_bit_cast(unsigned int, b);
    return ((ua + 0x8000u) >> 16) | ((ub + 0x8000u) & 0xffff0000u);
}

// W LDS tile: [144 rows][32 bf16] = 64B rows, 16B-slot swizzle.
__device__ __forceinline__ int swz32(int row, int kbyte) {
    return row * 64 + (kbyte ^ ((((row & 3) ^ ((row >> 2) & 1))) << 4));
}

// async global->LDS, 16B per lane
__device__ __forceinline__ void gload_lds16(const void* g, void* l) {
    __builtin_amdgcn_global_load_lds(
        (const __attribute__((address_space(1))) void*)g,
        (__attribute__((address_space(3))) void*)l, 16, 0, 0);
}

// ---------------- prep kernel: W f32 -> bf16, pre-swizzled into d_ws --------
__global__ __launch_bounds__(256)
void prep_w_kernel(const float* __restrict__ wb0, const float* __restrict__ wc0,
                   const float* __restrict__ wb1, const float* __restrict__ wc1,
                   const float* __restrict__ wb2, const float* __restrict__ wc2,
                   unsigned char* __restrict__ ws) {
    int uid = blockIdx.x * 256 + threadIdx.x;   // one unit = 8 k-elems
    if (uid >= 23040) return;                   // 4608 + 9216 + 9216
    const float* wb; const float* wc; int C; size_t off; int uu;
    if (uid < 4608)       { wb = wb0; wc = wc0; C = 256; off = WOFF0; uu = uid; }
    else if (uid < 13824) { wb = wb1; wc = wc1; C = 512; off = WOFF1; uu = uid - 4608; }
    else                  { wb = wb2; wc = wc2; C = 512; off = WOFF2; uu = uid - 13824; }
    const int kunits = C / 8;
    const int row = uu / kunits;
    const int k   = (uu % kunits) * 8;
    const float* src = ((row < 64) ? (wb + row * C) : (wc + (row - 64) * C)) + k;
    const float4 f0 = *(const float4*)(src);
    const float4 f1 = *(const float4*)(src + 4);
    uint4 p;
    p.x = pack_bf16(f0.x, f0.y);
    p.y = pack_bf16(f0.z, f0.w);
    p.z = pack_bf16(f1.x, f1.y);
    p.w = pack_bf16(f1.z, f1.w);
    const int chunk = k >> 5;            // 32-k chunks
    const int kg    = (k & 31) >> 3;     // 16B slot within row
    *(uint4*)(ws + off + (size_t)chunk * WCHUNK + swz32(row, kg * 16)) = p;
}

// ---------------- main kernel ----------------------------------------------
template <int LVL>
__device__ __forceinline__ void run_level(
        int rb,
        const float* __restrict__ x,
        const unsigned char* __restrict__ wimg_all,
        const float* __restrict__ bbox, const float* __restrict__ bcls,
        float* __restrict__ out,
        unsigned char* s_w, unsigned char* s_x) {

    constexpr int    C      = (LVL == 0) ? 256 : 512;
    constexpr int    GW     = (LVL == 0) ? 80 : (LVL == 1 ? 40 : 20);
    constexpr int    HW     = GW * GW;
    constexpr int    AOFF   = (LVL == 0) ? 0 : (LVL == 1 ? 6400 : 8000);
    constexpr float  STRIDE = (LVL == 0) ? 8.0f : (LVL == 1 ? 16.0f : 32.0f);
    constexpr int    TPB    = (HW + 127) / 128;  // 128-anchor tiles per image
    constexpr size_t WOFF   = (LVL == 0) ? WOFF0 : (LVL == 1 ? WOFF1 : WOFF2);
    const int nkc = C / 32;

    const int b    = rb / TPB;
    const int tile = rb % TPB;
    int hw0 = tile * 128;
    if (hw0 > HW - 128) hw0 = HW - 128;   // tail tiles overlap previous tile

    const int tid  = threadIdx.x;
    const int wv   = tid >> 6;        // wave 0..3
    const int lane = tid & 63;
    const int col  = lane & 15;       // MFMA n/col lane
    const int q4   = lane >> 4;       // MFMA row-quarter

    const float* xlev = x + (size_t)b * C * HW;
    const unsigned char* wimg = wimg_all + WOFF;

    // X DMA: wave wv stages rows wv*8..wv*8+7 (4 instr x 2 rows). Source
    // anchor-group pre-permuted by wv so swizzled reads see linear data.
    const int xg  = (((lane & 31) ^ (wv << 2)) << 2);  // anchor offset (4/grp)
    const int xr  = lane >> 5;                          // row parity
    // X frag read bases: byte = r*512 + ((a<<2) ^ (q4<<6)), a = wv*32+f*16+col
    const int xrd0 = (((wv * 32 + col) << 2) ^ (q4 << 6)) + q4 * 8 * 512;
    const int xrd1 = (((wv * 32 + 16 + col) << 2) ^ (q4 << 6)) + q4 * 8 * 512;

    f32x4 acc[9][2];
#pragma unroll
    for (int m = 0; m < 9; ++m) {
        acc[m][0] = (f32x4){0.f, 0.f, 0.f, 0.f};
        acc[m][1] = (f32x4){0.f, 0.f, 0.f, 0.f};
    }

#define XDMA(CC, BUF)                                                       \
    {                                                                       \
        _Pragma("unroll")                                                   \
        for (int _i = 0; _i < 4; ++_i) {                                    \
            const int _r2 = wv * 8 + _i * 2;                                \
            gload_lds16(xlev + (size_t)((CC) * 32 + _r2 + xr) * HW + hw0 + xg, \
                        s_x + (BUF) * XBUF + _r2 * 512);                    \
        }                                                                   \
    }

#define WDMA(CC, BUF)                                                       \
    {                                                                       \
        _Pragma("unroll")                                                   \
        for (int _i = 0; _i < 3; ++_i) {                                    \
            const int _u = tid + _i * 256;                                  \
            if (_u < 576)                                                   \
                gload_lds16(wimg + (size_t)(CC) * WCHUNK + _u * 16,         \
                            s_w + (BUF) * WCHUNK + _u * 16);                \
        }                                                                   \
    }

    // ---- prologue: stage chunk 0 ----
    XDMA(0, 0);
    WDMA(0, 0);
    __builtin_amdgcn_sched_barrier(0);
    asm volatile("s_waitcnt vmcnt(0)" ::: "memory");
    __builtin_amdgcn_s_barrier();
    __builtin_amdgcn_sched_barrier(0);

    for (int kc = 0; kc < nkc; ++kc) {
        const int cur = kc & 1;
        const bool more = (kc + 1 < nkc);

        if (more) {                      // issue next chunk's DMAs first
            XDMA(kc + 1, cur ^ 1);
            WDMA(kc + 1, cur ^ 1);
        }
        __builtin_amdgcn_sched_barrier(0);

        // ---- X fragments from LDS (swizzled, 2-way-free) + convert ----
        const unsigned char* xbuf = s_x + cur * XBUF;
        float xf0[8], xf1[8];
#pragma unroll
        for (int j = 0; j < 8; ++j) {
            xf0[j] = *(const float*)(xbuf + xrd0 + j * 512);
            xf1[j] = *(const float*)(xbuf + xrd1 + j * 512);
        }
        uint4 qa, qb;
        qa.x = pack_bf16(xf0[0], xf0[1]); qa.y = pack_bf16(xf0[2], xf0[3]);
        qa.z = pack_bf16(xf0[4], xf0[5]); qa.w = pack_bf16(xf0[6], xf0[7]);
        qb.x = pack_bf16(xf1[0], xf1[1]); qb.y = pack_bf16(xf1[2], xf1[3]);
        qb.z = pack_bf16(xf1[4], xf1[5]); qb.w = pack_bf16(xf1[6], xf1[7]);
        const bf16x8 fA = __builtin_bit_cast(bf16x8, qa);
        const bf16x8 fB = __builtin_bit_cast(bf16x8, qb);

        // ---- MFMA: 9 M-tiles x 2 N-frags; one A-read feeds 2 MFMAs ----
        const unsigned char* wbuf = s_w + cur * WCHUNK;
#pragma unroll
        for (int m = 0; m < 9; ++m) {
            const bf16x8 a_ = *(const bf16x8*)(wbuf + swz32(m * 16 + col, q4 * 16));
            acc[m][0] = __builtin_amdgcn_mfma_f32_16x16x32_bf16(a_, fA, acc[m][0], 0, 0, 0);
            acc[m][1] = __builtin_amdgcn_mfma_f32_16x16x32_bf16(a_, fB, acc[m][1], 0, 0, 0);
        }
        __builtin_amdgcn_sched_barrier(0);

        if (more) {
            asm volatile("s_waitcnt vmcnt(0)" ::: "memory");  // own 7 DMAs done
            __builtin_amdgcn_s_barrier();
            __builtin_amdgcn_sched_barrier(0);
        }
    }

#undef WDMA
#undef XDMA

    // ---- epilogue: in-register DFL decode + store ----
    // D layout (m89): value[r] = D[mtile*16 + q4*4 + r][col]
    float4 bcv[5];
#pragma unroll
    for (int m = 0; m < 5; ++m)
        bcv[m] = *(const float4*)(bcls + m * 16 + q4 * 4);

    const float LOG2E = 1.44269504088896f;

#pragma unroll
    for (int nf = 0; nf < 2; ++nf) {
        const int alocal = wv * 32 + nf * 16 + col;
        const int hw = hw0 + alocal;

        float dist[4];
#pragma unroll
        for (int g = 0; g < 4; ++g) {
            const float4 bbv = *(const float4*)(bbox + g * 16 + q4 * 4);
            const float v0 = acc[g][nf][0] + bbv.x;
            const float v1 = acc[g][nf][1] + bbv.y;
            const float v2 = acc[g][nf][2] + bbv.z;
            const float v3 = acc[g][nf][3] + bbv.w;
            // softmax over 16 bins: 4 regs x 4 lanes (col, col+16, col+32, col+48)
            float mx = fmaxf(fmaxf(v0, v1), fmaxf(v2, v3));
            mx = fmaxf(mx, __shfl_xor(mx, 16));
            mx = fmaxf(mx, __shfl_xor(mx, 32));
            const float e0 = __builtin_amdgcn_exp2f((v0 - mx) * LOG2E);
            const float e1 = __builtin_amdgcn_exp2f((v1 - mx) * LOG2E);
            const float e2 = __builtin_amdgcn_exp2f((v2 - mx) * LOG2E);
            const float e3 = __builtin_amdgcn_exp2f((v3 - mx) * LOG2E);
            float s  = e0 + e1 + e2 + e3;
            float ws = e1 + 2.f * e2 + 3.f * e3 + (float)(q4 * 4) * s;
            s  += __shfl_xor(s, 16);
            s  += __shfl_xor(s, 32);
            ws += __shfl_xor(ws, 16);
            ws += __shfl_xor(ws, 32);
            dist[g] = ws / s;
        }

        const size_t obase = ((size_t)b * 8400 + AOFF + hw) * 84;
        if (q4 == 0) {
            const float ax = (float)(hw % GW) + 0.5f;
            const float ay = (float)(hw / GW) + 0.5f;
            f32x4 bx;
            bx[0] = (ax + 0.5f * (dist[2] - dist[0])) * STRIDE;
            bx[1] = (ay + 0.5f * (dist[3] - dist[1])) * STRIDE;
            bx[2] = (dist[0] + dist[2]) * STRIDE;
            bx[3] = (dist[1] + dist[3]) * STRIDE;
            *(f32x4*)(out + obase) = bx;
        }
#pragma unroll
        for (int m = 0; m < 5; ++m) {
            f32x4 v;
            v[0] = acc[m + 4][nf][0] + bcv[m].x;
            v[1] = acc[m + 4][nf][1] + bcv[m].y;
            v[2] = acc[m + 4][nf][2] + bcv[m].z;
            v[3] = acc[m + 4][nf][3] + bcv[m].w;
            *(f32x4*)(out + obase + 4 + m * 16 + q4 * 4) = v;
        }
    }
}

__global__ __launch_bounds__(NTHREADS, 3)
void UltralyticsDetect_kernel(
        const float* __restrict__ x0, const float* __restrict__ x1, const float* __restrict__ x2,
        const unsigned char* __restrict__ wimg,
        const float* __restrict__ bb0, const float* __restrict__ bc0,
        const float* __restrict__ bb1, const float* __restrict__ bc1,
        const float* __restrict__ bb2, const float* __restrict__ bc2,
        float* __restrict__ out) {

    __shared__ __align__(16) unsigned char s_w[2 * WCHUNK];  // 18 KiB dbuf
    __shared__ __align__(16) unsigned char s_x[2 * XBUF];    // 32 KiB dbuf

    const int bid = blockIdx.x;
    // Long (K=512) levels first so the tail is filled by short level-0 blocks:
    // level 1: 16 b * 13 tiles = 208 ; level 2: 16*4 = 64 ; level 0: 16*50 = 800
    if (bid < 208) {
        run_level<1>(bid, x1, wimg, bb1, bc1, out, s_w, s_x);
    } else if (bid < 272) {
        run_level<2>(bid - 208, x2, wimg, bb2, bc2, out, s_w, s_x);
    } else {
        run_level<0>(bid - 272, x0, wimg, bb0, bc0, out, s_w, s_x);
    }
}

extern "C" void kernel_launch(void* const* d_in, const int* in_sizes, int n_in,
                              void* d_out, int out_size, void* d_ws, size_t ws_size,
                              hipStream_t stream) {
    const float* x0  = (const float*)d_in[0];
    const float* x1  = (const float*)d_in[1];
    const float* x2  = (const float*)d_in[2];
    const float* wb0 = (const float*)d_in[3];
    const float* bb0 = (const float*)d_in[4];
    const float* wc0 = (const float*)d_in[5];
    const float* bc0 = (const float*)d_in[6];
    const float* wb1 = (const float*)d_in[7];
    const float* bb1 = (const float*)d_in[8];
    const float* wc1 = (const float*)d_in[9];
    const float* bc1 = (const float*)d_in[10];
    const float* wb2 = (const float*)d_in[11];
    const float* bb2 = (const float*)d_in[12];
    const float* wc2 = (const float*)d_in[13];
    const float* bc2 = (const float*)d_in[14];

    unsigned char* wimg = (unsigned char*)d_ws;

    prep_w_kernel<<<90, 256, 0, stream>>>(wb0, wc0, wb1, wc1, wb2, wc2, wimg);

    UltralyticsDetect_kernel<<<1072, NTHREADS, 0, stream>>>(
        x0, x1, x2, wimg,
        bb0, bc0, bb1, bc1, bb2, bc2,
        (float*)d_out);
}